// Round 1
// baseline (311.120 us; speedup 1.0000x reference)
//
#include <hip/hip_runtime.h>
#include <hip/hip_bf16.h>
#include <stdint.h>

typedef __attribute__((ext_vector_type(8))) short bf16x8;
typedef __attribute__((ext_vector_type(4))) float f32x4;

#define B_    2
#define HIN   256
#define WIN   256
#define HOUT  32
#define WOUT  32
#define CG    5
#define CF    261
#define KDIM  256
#define NP    2048
#define NBANK 65536

__device__ inline short f2bf(float f) {
  __hip_bfloat16 h = __float2bfloat16(f);
  return *reinterpret_cast<short*>(&h);
}

// ---------------- Kernel 1: antialiased bilinear resize 256->32 -------------
// jax.image.resize(method='bilinear', antialias=True): sample at 8i+3.5,
// triangle kernel scaled by 8 -> 16 taps/dim, renormalized over valid taps.
__global__ void k_resize(const float* __restrict__ geo, float* __restrict__ geo_rs) {
  int idx = blockIdx.x * 256 + threadIdx.x;           // 2*5*32*32 = 10240
  if (idx >= B_ * CG * HOUT * WOUT) return;
  int j = idx & 31, i = (idx >> 5) & 31;
  int bc = idx >> 10;                                  // b*5+cg
  const float* src = geo + (size_t)bc * HIN * WIN;

  float colw[16]; float norm_c = 0.f;
  #pragma unroll
  for (int t = 0; t < 16; t++) {
    int k = 8 * j - 4 + t;
    float w = 1.f - fabsf((float)t - 7.5f) * 0.125f;
    if (k >= 0 && k < WIN) { colw[t] = w; norm_c += w; } else colw[t] = 0.f;
  }
  float acc = 0.f, norm_r = 0.f;
  for (int ti = 0; ti < 16; ti++) {
    int kr = 8 * i - 4 + ti;
    if (kr < 0 || kr >= HIN) continue;
    float wr = 1.f - fabsf((float)ti - 7.5f) * 0.125f;
    norm_r += wr;
    const float* row = src + (size_t)kr * WIN;
    float rs = 0.f;
    #pragma unroll
    for (int tj = 0; tj < 16; tj++) {
      if (colw[tj] != 0.f) rs += colw[tj] * row[8 * j - 4 + tj];
    }
    acc += wr * rs;
  }
  geo_rs[idx] = acc / (norm_r * norm_c);
}

// ---------------- Kernel 2: conv(8x8 stride 8)+relu + fusion matmul ---------
// One block = 8 horizontally-consecutive output positions (same b,h).
// Produces flat_bf16[2048][256], qsq[2048], wgt[2048].
__global__ __launch_bounds__(256) void k_convfuse(
    const float* __restrict__ image, const float* __restrict__ geo_rs,
    const float* __restrict__ bw, const float* __restrict__ bb,
    const float* __restrict__ fw, const float* __restrict__ fb,
    short* __restrict__ flatb, float* __restrict__ qsq, float* __restrict__ wgt)
{
  __shared__ float patch[3 * 8 * 64];     // 6 KB: [c][r][64 cols]
  __shared__ float fused[8][264];         // 8 positions x 261(+pad) channels
  __shared__ float red[4][8];
  int t = threadIdx.x;
  int blk = blockIdx.x;                   // 256 blocks = 2 * 32 * 4
  int b = blk >> 7, rem = blk & 127, h = rem >> 2, wq = rem & 3;
  int w0 = wq * 8;

  // stage 3x8x64 image patch (covers the 8 positions)
  #pragma unroll
  for (int j = 0; j < 6; j++) {
    int idx = t + j * 256;
    int c = idx >> 9, r = (idx >> 6) & 7, col = idx & 63;
    patch[idx] = image[(((size_t)(b * 3 + c) * HIN) + 8 * h + r) * WIN + 8 * w0 + col];
  }
  __syncthreads();

  // conv: thread t = output channel
  float acc[8];
  #pragma unroll
  for (int i = 0; i < 8; i++) acc[i] = 0.f;
  const float* wo = bw + t * 192;
  for (int cr = 0; cr < 24; cr++) {       // (c,r) pairs
    const float* prow = &patch[cr * 64];
    #pragma unroll
    for (int cl = 0; cl < 8; cl++) {
      float wv = wo[cr * 8 + cl];
      #pragma unroll
      for (int i = 0; i < 8; i++) acc[i] += wv * prow[i * 8 + cl];
    }
  }
  float bias = bb[t];
  #pragma unroll
  for (int i = 0; i < 8; i++) fused[i][t] = fmaxf(acc[i] + bias, 0.f);
  if (t < 40) {
    int i = t / 5, cg = t % 5;
    fused[i][256 + cg] = geo_rs[((size_t)(b * CG + cg) * HOUT + h) * WOUT + w0 + i];
  }
  __syncthreads();

  // fusion: out[o] = fb[o] + sum_c fw[o,c]*fused[c]
  #pragma unroll
  for (int i = 0; i < 8; i++) acc[i] = 0.f;
  const float* fwo = fw + (size_t)t * CF;
  for (int c = 0; c < CF; c++) {
    float wv = fwo[c];
    #pragma unroll
    for (int i = 0; i < 8; i++) acc[i] += wv * fused[i][c];
  }
  float fbias = fb[t];
  #pragma unroll
  for (int i = 0; i < 8; i++) acc[i] += fbias;

  int lane = t & 63, wvid = t >> 6;
  for (int i = 0; i < 8; i++) {
    int p = b * 1024 + h * 32 + w0 + i;
    flatb[(size_t)p * KDIM + t] = f2bf(acc[i]);
    float s = acc[i] * acc[i];
    for (int m = 1; m < 64; m <<= 1) s += __shfl_xor(s, m);
    if (lane == 0) red[wvid][i] = s;
  }
  __syncthreads();
  if (t < 8) {
    float s = red[0][t] + red[1][t] + red[2][t] + red[3][t];
    int p = b * 1024 + h * 32 + w0 + t;
    qsq[p] = s;
    float den = fused[t][256 + 3], opa = fused[t][256 + 2], ani = fused[t][256 + 4];
    float base = 0.5f * den + 0.25f * (1.f - opa) + 0.25f * ani;
    float sg = 1.f / (1.f + expf(-4.f * (base - 0.5f)));
    wgt[p] = 1.f + sg;
  }
}

// ---------------- Kernel 3: bank -> bf16 + row squared norms ----------------
__global__ __launch_bounds__(256) void k_bankprep(
    const float* __restrict__ mb, short* __restrict__ mbb, float* __restrict__ msq)
{
  int w = threadIdx.x >> 6, lane = threadIdx.x & 63;
  int row = blockIdx.x * 4 + w;
  const float4 v = reinterpret_cast<const float4*>(mb + (size_t)row * 256)[lane];
  short4 o; o.x = f2bf(v.x); o.y = f2bf(v.y); o.z = f2bf(v.z); o.w = f2bf(v.w);
  reinterpret_cast<short4*>(mbb + (size_t)row * 256)[lane] = o;
  float s = v.x * v.x + v.y * v.y + v.z * v.z + v.w * v.w;
  for (int m = 1; m < 64; m <<= 1) s += __shfl_xor(s, m);
  if (lane == 0) msq[row] = s;
}

// ---------------- Kernel 4: GEMM-min  (128x128 tile, BK=64, bf16 MFMA) ------
// A = queries [2048][256] bf16, B = bank [65536][256] bf16 (B^T layout fits
// the MFMA B-operand directly: lane holds row n's k-slice).
// LDS tiles XOR-swizzled (T2): linear dest for global_load_lds, pre-swizzled
// global source, same XOR on ds_read (both-sides rule, m201/m104).
__global__ __launch_bounds__(256) void k_distmin(
    const short* __restrict__ Aq, const short* __restrict__ Bb,
    const float* __restrict__ qsq, const float* __restrict__ msq,
    float* __restrict__ partial)
{
  __shared__ __align__(16) unsigned char sA[16384];   // [128][64] bf16 swizzled
  __shared__ __align__(16) unsigned char sB[16384];
  __shared__ float red[2][128];
  int t = threadIdx.x;
  int lane = t & 63, wid = t >> 6;
  int wr = wid >> 1, wc = wid & 1;
  int bm = blockIdx.y, bn = blockIdx.x;
  int m0 = bm * 128, n0 = bn * 128;
  const int l15 = lane & 15, l4 = lane >> 4;

  f32x4 acc[4][4];
  #pragma unroll
  for (int i = 0; i < 4; i++)
    #pragma unroll
    for (int j = 0; j < 4; j++) acc[i][j] = (f32x4){0.f, 0.f, 0.f, 0.f};

  for (int ks = 0; ks < 4; ks++) {
    int k0 = ks * 64;
    __syncthreads();
    #pragma unroll
    for (int q = 0; q < 4; q++) {
      int X = q * 4096 + t * 16;              // linear LDS byte
      int m = X >> 7;                         // tile row (128B rows)
      int inrow = X & 127;
      int srow = inrow ^ ((m & 7) << 4);      // inverse-swizzled source bytes
      const unsigned char* ga = (const unsigned char*)Aq + (size_t)(m0 + m) * 512 + k0 * 2 + srow;
      __builtin_amdgcn_global_load_lds(
          (const __attribute__((address_space(1))) unsigned int*)ga,
          (__attribute__((address_space(3))) unsigned int*)(sA + q * 4096 + (t >> 6) * 1024),
          16, 0, 0);
      const unsigned char* gb = (const unsigned char*)Bb + (size_t)(n0 + m) * 512 + k0 * 2 + srow;
      __builtin_amdgcn_global_load_lds(
          (const __attribute__((address_space(1))) unsigned int*)gb,
          (__attribute__((address_space(3))) unsigned int*)(sB + q * 4096 + (t >> 6) * 1024),
          16, 0, 0);
    }
    __syncthreads();

    #pragma unroll
    for (int kk = 0; kk < 64; kk += 32) {
      bf16x8 af[4], bfr[4];
      #pragma unroll
      for (int mi = 0; mi < 4; mi++) {
        int m = wr * 64 + mi * 16 + l15;
        int off = (m << 7) + ((kk + l4 * 8) << 1);
        off ^= (m & 7) << 4;
        af[mi] = *(const bf16x8*)(sA + off);
      }
      #pragma unroll
      for (int nj = 0; nj < 4; nj++) {
        int n = wc * 64 + nj * 16 + l15;
        int off = (n << 7) + ((kk + l4 * 8) << 1);
        off ^= (n & 7) << 4;
        bfr[nj] = *(const bf16x8*)(sB + off);
      }
      #pragma unroll
      for (int mi = 0; mi < 4; mi++)
        #pragma unroll
        for (int nj = 0; nj < 4; nj++)
          acc[mi][nj] = __builtin_amdgcn_mfma_f32_16x16x32_bf16(af[mi], bfr[nj], acc[mi][nj], 0, 0, 0);
    }
  }

  // epilogue: per query-row min over this block's 128 bank cols
  float msqv[4];
  #pragma unroll
  for (int nj = 0; nj < 4; nj++) msqv[nj] = msq[n0 + wc * 64 + nj * 16 + l15];
  #pragma unroll
  for (int mi = 0; mi < 4; mi++) {
    #pragma unroll
    for (int r = 0; r < 4; r++) {
      float v =          msqv[0] - 2.f * acc[mi][0][r];
      v = fminf(v, msqv[1] - 2.f * acc[mi][1][r]);
      v = fminf(v, msqv[2] - 2.f * acc[mi][2][r]);
      v = fminf(v, msqv[3] - 2.f * acc[mi][3][r]);
      v = fminf(v, __shfl_xor(v, 1));
      v = fminf(v, __shfl_xor(v, 2));
      v = fminf(v, __shfl_xor(v, 4));
      v = fminf(v, __shfl_xor(v, 8));
      if (l15 == 0) red[wc][wr * 64 + mi * 16 + l4 * 4 + r] = v;
    }
  }
  __syncthreads();
  if (t < 128) {
    float v = fminf(red[0][t], red[1][t]);
    float d2 = qsq[m0 + t] + v;
    partial[(size_t)(m0 + t) * 512 + bn] = fmaxf(d2, 0.f);
  }
}

// ---------------- Kernel 5: final min + sqrt + geo weight -------------------
__global__ __launch_bounds__(256) void k_final(
    const float* __restrict__ partial, const float* __restrict__ wgt,
    float* __restrict__ out)
{
  int w = threadIdx.x >> 6, lane = threadIdx.x & 63;
  int q = blockIdx.x * 4 + w;
  const float* p = partial + (size_t)q * 512;
  float v = 3.4e38f;
  #pragma unroll
  for (int s = 0; s < 8; s++) v = fminf(v, p[lane + s * 64]);
  for (int m = 1; m < 64; m <<= 1) v = fminf(v, __shfl_xor(v, m));
  if (lane == 0) {
    float sp = sqrtf(v);
    out[q] = sp;
    out[NP + q] = sp * wgt[q];
  }
}

extern "C" void kernel_launch(void* const* d_in, const int* in_sizes, int n_in,
                              void* d_out, int out_size, void* d_ws, size_t ws_size,
                              hipStream_t stream) {
  const float* image    = (const float*)d_in[0];
  const float* geometry = (const float*)d_in[1];
  const float* bw       = (const float*)d_in[2];
  const float* bb       = (const float*)d_in[3];
  const float* fw       = (const float*)d_in[4];
  const float* fb       = (const float*)d_in[5];
  const float* mb       = (const float*)d_in[6];
  float* out = (float*)d_out;
  char* ws = (char*)d_ws;

  float* geo_rs  = (float*)(ws);                 // 40960 B
  float* wgt     = (float*)(ws + 40960);         // 8 KB
  float* qsq     = (float*)(ws + 49152);         // 8 KB
  float* msq     = (float*)(ws + 57344);         // 256 KB
  short* flatb   = (short*)(ws + 319488);        // 1 MB
  float* partial = (float*)(ws + 1368064);       // 4 MB  [2048][512]
  short* mbb     = (short*)(ws + 5562368);       // 32 MB [65536][256] bf16

  hipLaunchKernelGGL(k_resize,   dim3(40),       dim3(256), 0, stream, geometry, geo_rs);
  hipLaunchKernelGGL(k_convfuse, dim3(256),      dim3(256), 0, stream, image, geo_rs, bw, bb, fw, fb, flatb, qsq, wgt);
  hipLaunchKernelGGL(k_bankprep, dim3(16384),    dim3(256), 0, stream, mb, mbb, msq);
  hipLaunchKernelGGL(k_distmin,  dim3(512, 16),  dim3(256), 0, stream, flatb, mbb, qsq, msq, partial);
  hipLaunchKernelGGL(k_final,    dim3(512),      dim3(256), 0, stream, partial, wgt, out);
}

// Round 3
// 217.773 us; speedup vs baseline: 1.4286x; 1.4286x over previous
//
#include <hip/hip_runtime.h>
#include <hip/hip_bf16.h>
#include <stdint.h>

typedef __attribute__((ext_vector_type(8))) short bf16x8;
typedef __attribute__((ext_vector_type(4))) float f32x4;

#define B_    2
#define HIN   256
#define WIN   256
#define HOUT  32
#define WOUT  32
#define CG    5
#define CF    261
#define KDIM  256
#define NP    2048
#define NBANK 65536
#define NCHUNKS 32
#define CHUNK  2048
#define SUBR   64
#define NSUB   32

__device__ inline short f2bf(float f) {
  __hip_bfloat16 h = __float2bfloat16(f);
  return *reinterpret_cast<short*>(&h);
}

// ---------------- resize: separable antialiased bilinear 256->32 ------------
// pass 1: horizontal. out tmp[bc][256 rows][32 cols]
__global__ __launch_bounds__(256) void k_resize_h(
    const float* __restrict__ geo, float* __restrict__ tmp)
{
  int idx = blockIdx.x * 256 + threadIdx.x;      // 2*5*256*32 = 81920
  int j = idx & 31, row = (idx >> 5) & 255, bc = idx >> 13;
  const float* src = geo + ((size_t)bc * HIN + row) * WIN;
  float acc = 0.f, norm = 0.f;
  #pragma unroll
  for (int t = 0; t < 16; t++) {
    int k = 8 * j - 4 + t;
    float w = 1.f - fabsf((float)t - 7.5f) * 0.125f;
    if (k >= 0 && k < WIN) { acc += w * src[k]; norm += w; }
  }
  tmp[idx] = acc / norm;
}
// pass 2: vertical. out geo_rs[bc][32][32]
__global__ __launch_bounds__(256) void k_resize_v(
    const float* __restrict__ tmp, float* __restrict__ geo_rs)
{
  int idx = blockIdx.x * 256 + threadIdx.x;      // 10240
  if (idx >= B_ * CG * HOUT * WOUT) return;
  int j = idx & 31, i = (idx >> 5) & 31, bc = idx >> 10;
  const float* col = tmp + (size_t)bc * 8192 + j;
  float acc = 0.f, norm = 0.f;
  #pragma unroll
  for (int t = 0; t < 16; t++) {
    int k = 8 * i - 4 + t;
    float w = 1.f - fabsf((float)t - 7.5f) * 0.125f;
    if (k >= 0 && k < HIN) { acc += w * col[(size_t)k * 32]; norm += w; }
  }
  geo_rs[idx] = acc / norm;
}

// ---------------- fw repack: [256][261] -> [256][264] (16B rows, zero pad) --
__global__ __launch_bounds__(256) void k_repack_fw(
    const float* __restrict__ fw, float* __restrict__ fwp)
{
  int idx = blockIdx.x * 256 + threadIdx.x;      // 256*264 = 67584
  int o = idx / 264, c = idx % 264;
  fwp[idx] = (c < CF) ? fw[(size_t)o * CF + c] : 0.f;
}

// ---------------- conv(8x8 s8)+relu + fusion matmul (float4 weights) --------
__global__ __launch_bounds__(256) void k_convfuse(
    const float* __restrict__ image, const float* __restrict__ geo_rs,
    const float* __restrict__ bw, const float* __restrict__ bb,
    const float* __restrict__ fwp, const float* __restrict__ fb,
    short* __restrict__ flatb, float* __restrict__ qsq, float* __restrict__ wgt)
{
  __shared__ float patch[3 * 8 * 64];
  __shared__ float fused[8][264];
  __shared__ float red[4][8];
  int t = threadIdx.x;
  int blk = blockIdx.x;                   // 256 = 2 * 32 * 4
  int b = blk >> 7, rem = blk & 127, h = rem >> 2, wq = rem & 3;
  int w0 = wq * 8;

  #pragma unroll
  for (int j = 0; j < 6; j++) {
    int idx = t + j * 256;
    int c = idx >> 9, r = (idx >> 6) & 7, col = idx & 63;
    patch[idx] = image[(((size_t)(b * 3 + c) * HIN) + 8 * h + r) * WIN + 8 * w0 + col];
  }
  if (t < 24) { int i = t / 3, c = 261 + t % 3; fused[i][c] = 0.f; }
  __syncthreads();

  float acc[8];
  #pragma unroll
  for (int i = 0; i < 8; i++) acc[i] = 0.f;
  const float4* wo4 = (const float4*)(bw + (size_t)t * 192);
  for (int cr = 0; cr < 24; cr++) {
    const float* prow = &patch[cr * 64];
    #pragma unroll
    for (int half = 0; half < 2; half++) {
      float4 w = wo4[cr * 2 + half];
      #pragma unroll
      for (int e = 0; e < 4; e++) {
        float wv = (&w.x)[e];
        int cl = half * 4 + e;
        #pragma unroll
        for (int i = 0; i < 8; i++) acc[i] += wv * prow[i * 8 + cl];
      }
    }
  }
  float bias = bb[t];
  #pragma unroll
  for (int i = 0; i < 8; i++) fused[i][t] = fmaxf(acc[i] + bias, 0.f);
  if (t < 40) {
    int i = t / 5, cg = t % 5;
    fused[i][256 + cg] = geo_rs[((size_t)(b * CG + cg) * HOUT + h) * WOUT + w0 + i];
  }
  __syncthreads();

  #pragma unroll
  for (int i = 0; i < 8; i++) acc[i] = 0.f;
  const float4* fwo4 = (const float4*)(fwp + (size_t)t * 264);
  for (int c4 = 0; c4 < 66; c4++) {
    float4 w = fwo4[c4];
    #pragma unroll
    for (int e = 0; e < 4; e++) {
      float wv = (&w.x)[e];
      int c = c4 * 4 + e;
      #pragma unroll
      for (int i = 0; i < 8; i++) acc[i] += wv * fused[i][c];
    }
  }
  float fbias = fb[t];
  #pragma unroll
  for (int i = 0; i < 8; i++) acc[i] += fbias;

  int lane = t & 63, wvid = t >> 6;
  for (int i = 0; i < 8; i++) {
    int p = b * 1024 + h * 32 + w0 + i;
    flatb[(size_t)p * KDIM + t] = f2bf(acc[i]);
    float s = acc[i] * acc[i];
    for (int m = 1; m < 64; m <<= 1) s += __shfl_xor(s, m);
    if (lane == 0) red[wvid][i] = s;
  }
  __syncthreads();
  if (t < 8) {
    float s = red[0][t] + red[1][t] + red[2][t] + red[3][t];
    int p = b * 1024 + h * 32 + w0 + t;
    qsq[p] = s;
    float den = fused[t][256 + 3], opa = fused[t][256 + 2], ani = fused[t][256 + 4];
    float base = 0.5f * den + 0.25f * (1.f - opa) + 0.25f * ani;
    float sg = 1.f / (1.f + expf(-4.f * (base - 0.5f)));
    wgt[p] = 1.f + sg;
  }
}

// ---------------- bank -> bf16 + row squared norms --------------------------
__global__ __launch_bounds__(256) void k_bankprep(
    const float* __restrict__ mb, short* __restrict__ mbb, float* __restrict__ msq)
{
  int w = threadIdx.x >> 6, lane = threadIdx.x & 63;
  int row = blockIdx.x * 4 + w;
  const float4 v = reinterpret_cast<const float4*>(mb + (size_t)row * 256)[lane];
  short4 o; o.x = f2bf(v.x); o.y = f2bf(v.y); o.z = f2bf(v.z); o.w = f2bf(v.w);
  reinterpret_cast<short4*>(mbb + (size_t)row * 256)[lane] = o;
  float s = v.x * v.x + v.y * v.y + v.z * v.z + v.w * v.w;
  for (int m = 1; m < 64; m <<= 1) s += __shfl_xor(s, m);
  if (lane == 0) msq[row] = s;
}

// ---------------- GEMM-min: persistent-A, streamed B, 2-phase dbuf ----------
// Grid (32 n-chunks, 16 m-tiles). Block: 4 waves (wr=wid>>1, wc=wid&1),
// per-wave output 64 rows x 32 cols per subtile. A tile 128x256 bf16 held in
// registers (32 frags/lane). B streamed in 64-row subtiles, XOR-swizzled LDS
// (linear dest + inverse-swizzled global source, rule #21).
__global__ __launch_bounds__(256, 2) void k_distmin(
    const short* __restrict__ Aq, const short* __restrict__ Bb,
    const float* __restrict__ qsq, const float* __restrict__ msq,
    float* __restrict__ partial)
{
  __shared__ __align__(16) unsigned char sB[2][32768];
  __shared__ float red[2][128];
  int t = threadIdx.x;
  int lane = t & 63, wid = t >> 6;
  int wr = wid >> 1, wc = wid & 1;
  const int l15 = lane & 15, l4 = lane >> 4;
  int nc = blockIdx.x, mt = blockIdx.y;
  int m0 = mt * 128;
  const size_t nchunk0 = (size_t)nc * CHUNK;
  const unsigned char* Bbyte = (const unsigned char*)Bb;
  const unsigned char* Abyte = (const unsigned char*)Aq;

#define STAGE(dstbase, nbase) do {                                            \
    _Pragma("unroll")                                                         \
    for (int j = 0; j < 8; j++) {                                             \
      int X = j * 4096 + wid * 1024 + lane * 16;                              \
      int r_ = X >> 9, inrow = X & 511;                                       \
      int srow = inrow ^ ((r_ & 7) << 4);                                     \
      const unsigned char* g = Bbyte + ((size_t)(nbase) + r_) * 512 + srow;   \
      __builtin_amdgcn_global_load_lds(                                       \
          (const __attribute__((address_space(1))) unsigned int*)g,           \
          (__attribute__((address_space(3))) unsigned int*)((dstbase) + j * 4096 + wid * 1024), \
          16, 0, 0);                                                          \
    }                                                                         \
  } while (0)

  // A tile -> registers: af[mi][ks], rows m0+wr*64+mi*16+l15, k = ks*32+l4*8
  bf16x8 af[4][8];
  #pragma unroll
  for (int mi = 0; mi < 4; mi++)
    #pragma unroll
    for (int ks = 0; ks < 8; ks++)
      af[mi][ks] = *(const bf16x8*)(Abyte +
          (size_t)(m0 + wr * 64 + mi * 16 + l15) * 512 + ks * 64 + l4 * 16);

  float vmin[4][4];
  #pragma unroll
  for (int mi = 0; mi < 4; mi++)
    #pragma unroll
    for (int r = 0; r < 4; r++) vmin[mi][r] = 3.4e38f;

  STAGE(&sB[0][0], nchunk0);
  __syncthreads();

  int cur = 0;
  for (int s = 0; s < NSUB; s++) {
    if (s + 1 < NSUB) STAGE(&sB[cur ^ 1][0], nchunk0 + (s + 1) * SUBR);
    const size_t nb = nchunk0 + (size_t)s * SUBR;
    float msq0 = msq[nb + wc * 32 + l15];
    float msq1 = msq[nb + wc * 32 + 16 + l15];
    const unsigned char* buf = &sB[cur][0];

    f32x4 acc[4][2];
    #pragma unroll
    for (int mi = 0; mi < 4; mi++) {
      acc[mi][0] = (f32x4){0.f, 0.f, 0.f, 0.f};
      acc[mi][1] = (f32x4){0.f, 0.f, 0.f, 0.f};
    }
    #pragma unroll
    for (int ks = 0; ks < 8; ks++) {
      bf16x8 b0, b1;
      {
        int n = wc * 32 + l15;
        int off = (n << 9) + ks * 64 + l4 * 16; off ^= (n & 7) << 4;
        b0 = *(const bf16x8*)(buf + off);
      }
      {
        int n = wc * 32 + 16 + l15;
        int off = (n << 9) + ks * 64 + l4 * 16; off ^= (n & 7) << 4;
        b1 = *(const bf16x8*)(buf + off);
      }
      #pragma unroll
      for (int mi = 0; mi < 4; mi++) {
        acc[mi][0] = __builtin_amdgcn_mfma_f32_16x16x32_bf16(af[mi][ks], b0, acc[mi][0], 0, 0, 0);
        acc[mi][1] = __builtin_amdgcn_mfma_f32_16x16x32_bf16(af[mi][ks], b1, acc[mi][1], 0, 0, 0);
      }
    }
    #pragma unroll
    for (int mi = 0; mi < 4; mi++)
      #pragma unroll
      for (int r = 0; r < 4; r++) {
        float v = fminf(msq0 - 2.f * acc[mi][0][r], msq1 - 2.f * acc[mi][1][r]);
        vmin[mi][r] = fminf(vmin[mi][r], v);
      }
    __syncthreads();
    cur ^= 1;
  }
#undef STAGE

  // deferred cross-lane min over the 16 l15 columns
  #pragma unroll
  for (int mi = 0; mi < 4; mi++)
    #pragma unroll
    for (int r = 0; r < 4; r++) {
      float v = vmin[mi][r];
      v = fminf(v, __shfl_xor(v, 1));
      v = fminf(v, __shfl_xor(v, 2));
      v = fminf(v, __shfl_xor(v, 4));
      v = fminf(v, __shfl_xor(v, 8));
      if (l15 == 0) red[wc][wr * 64 + mi * 16 + l4 * 4 + r] = v;
    }
  __syncthreads();
  if (t < 128) {
    float v = fminf(red[0][t], red[1][t]);
    float d2 = qsq[m0 + t] + v;
    partial[(size_t)(m0 + t) * NCHUNKS + nc] = fmaxf(d2, 0.f);
  }
}

// ---------------- final min + sqrt + geo weight -----------------------------
__global__ __launch_bounds__(256) void k_final(
    const float* __restrict__ partial, const float* __restrict__ wgt,
    float* __restrict__ out)
{
  int q = blockIdx.x * 256 + threadIdx.x;        // 2048
  const float4* p = (const float4*)(partial + (size_t)q * NCHUNKS);
  float v = 3.4e38f;
  #pragma unroll
  for (int j = 0; j < 8; j++) {
    float4 x = p[j];
    v = fminf(v, fminf(fminf(x.x, x.y), fminf(x.z, x.w)));
  }
  float sp = sqrtf(v);
  out[q] = sp;
  out[NP + q] = sp * wgt[q];
}

extern "C" void kernel_launch(void* const* d_in, const int* in_sizes, int n_in,
                              void* d_out, int out_size, void* d_ws, size_t ws_size,
                              hipStream_t stream) {
  const float* image    = (const float*)d_in[0];
  const float* geometry = (const float*)d_in[1];
  const float* bw       = (const float*)d_in[2];
  const float* bb       = (const float*)d_in[3];
  const float* fw       = (const float*)d_in[4];
  const float* fb       = (const float*)d_in[5];
  const float* mb       = (const float*)d_in[6];
  float* out = (float*)d_out;
  char* ws = (char*)d_ws;

  float* geo_rs  = (float*)(ws);                  // 40960 B
  float* tmp_rs  = (float*)(ws + 40960);          // 327680 B
  float* wgt     = (float*)(ws + 368640);         // 8 KB
  float* qsq     = (float*)(ws + 376832);         // 8 KB
  float* msq     = (float*)(ws + 385024);         // 256 KB
  float* fwp     = (float*)(ws + 647168);         // 270336 B
  short* flatb   = (short*)(ws + 917504);         // 1 MB
  float* partial = (float*)(ws + 1966080);        // 256 KB  [2048][32]
  short* mbb     = (short*)(ws + 2228224);        // 32 MB   [65536][256] bf16

  hipLaunchKernelGGL(k_resize_h,  dim3(320),      dim3(256), 0, stream, geometry, tmp_rs);
  hipLaunchKernelGGL(k_resize_v,  dim3(40),       dim3(256), 0, stream, tmp_rs, geo_rs);
  hipLaunchKernelGGL(k_repack_fw, dim3(264),      dim3(256), 0, stream, fw, fwp);
  hipLaunchKernelGGL(k_convfuse,  dim3(256),      dim3(256), 0, stream, image, geo_rs, bw, bb, fwp, fb, flatb, qsq, wgt);
  hipLaunchKernelGGL(k_bankprep,  dim3(16384),    dim3(256), 0, stream, mb, mbb, msq);
  hipLaunchKernelGGL(k_distmin,   dim3(32, 16),   dim3(256), 0, stream, flatb, mbb, qsq, msq, partial);
  hipLaunchKernelGGL(k_final,     dim3(8),        dim3(256), 0, stream, partial, wgt, out);
}

// Round 4
// 214.591 us; speedup vs baseline: 1.4498x; 1.0148x over previous
//
#include <hip/hip_runtime.h>
#include <hip/hip_bf16.h>
#include <stdint.h>

typedef __attribute__((ext_vector_type(8))) short bf16x8;
typedef __attribute__((ext_vector_type(4))) float f32x4;

#define NP 2048
#define NBANK 65536
#define NCHUNKS 32
#define CHUNK 2048
#define SUBR 64
#define NSUB 32
#define CF 261

__device__ inline short f2bf(float f) {
  __hip_bfloat16 h = __float2bfloat16(f);
  return *reinterpret_cast<short*>(&h);
}

// ---------------- fw repack: [256][261] -> [256][264] (16B rows, zero pad) --
__global__ __launch_bounds__(256) void k_repack_fw(
    const float* __restrict__ fw, float* __restrict__ fwp)
{
  int idx = blockIdx.x * 256 + threadIdx.x;      // 256*264 = 67584
  int o = idx / 264, c = idx % 264;
  fwp[idx] = (c < CF) ? fw[(size_t)o * CF + c] : 0.f;
}

// ---------------- prep: conv+resize+fusion (blocks 0..255) ------------------
// ----------------       bank->bf16+norms   (blocks 256..8447) ---------------
__global__ __launch_bounds__(512) void k_prep(
    const float* __restrict__ image, const float* __restrict__ geometry,
    const float* __restrict__ bw, const float* __restrict__ bb,
    const float* __restrict__ fwp, const float* __restrict__ fb,
    const float* __restrict__ mb,
    short* __restrict__ flatb, float* __restrict__ qsq, float* __restrict__ wgt,
    short* __restrict__ mbb, float* __restrict__ msq)
{
  __shared__ float patch[1536];
  __shared__ float fusedS[8][264];
  __shared__ float gv[40][8];
  __shared__ float gw[40][8];
  __shared__ float redS[8][8];
  int t = threadIdx.x;
  int bid = blockIdx.x;

  if (bid >= 256) {                       // ---- bank prep: 8 rows/block ----
    int row = (bid - 256) * 8 + (t >> 6);
    int lane = t & 63;
    float4 v = ((const float4*)(mb + (size_t)row * 256))[lane];
    short4 o; o.x = f2bf(v.x); o.y = f2bf(v.y); o.z = f2bf(v.z); o.w = f2bf(v.w);
    ((short4*)(mbb + (size_t)row * 256))[lane] = o;
    float s = v.x*v.x + v.y*v.y + v.z*v.z + v.w*v.w;
    #pragma unroll
    for (int m = 1; m < 64; m <<= 1) s += __shfl_xor(s, m);
    if (lane == 0) msq[row] = s;
    return;
  }

  // ---- conv part: block = (b, h, w-quad of 8 positions), 512 threads ----
  int b = bid >> 7, rem = bid & 127, h = rem >> 2, w0 = (rem & 3) * 8;

  #pragma unroll
  for (int j = 0; j < 3; j++) {           // stage 3x8x64 image patch
    int idx = t + j * 512;
    int c = idx >> 9, r = (idx >> 6) & 7, col = idx & 63;
    patch[idx] = image[(((size_t)(b*3 + c) * 256) + 8*h + r) * 256 + 8*w0 + col];
  }
  if (t >= 320 && t < 344) {              // zero pad fused[i][261..263]
    int i = (t - 320) / 3, c = 261 + (t - 320) % 3;
    fusedS[i][c] = 0.f;
  }
  if (t < 320) {                          // geo resize partials (8 subs/value)
    int v = t >> 3, sub = t & 7;
    int i = v / 5, cg = v % 5;
    int jj = w0 + i;
    float val = 0.f, ws = 0.f;
    const float* gch = geometry + (size_t)(b*5 + cg) * 65536;
    #pragma unroll
    for (int rr = 0; rr < 2; rr++) {
      int r = sub * 2 + rr;
      int gr = 8*h - 4 + r;
      float wr = 1.f - fabsf((float)r - 7.5f) * 0.125f;
      if (gr >= 0 && gr < 256) {
        const float* grow = gch + (size_t)gr * 256;
        for (int c = 0; c < 16; c++) {
          int gc = 8*jj - 4 + c;
          if (gc >= 0 && gc < 256) {
            float wc_ = 1.f - fabsf((float)c - 7.5f) * 0.125f;
            val += wr * wc_ * grow[gc];
            ws  += wr * wc_;
          }
        }
      }
    }
    gv[v][sub] = val; gw[v][sub] = ws;
  }
  __syncthreads();
  if (t < 40) {                           // combine resize partials
    int i = t / 5, cg = t % 5;
    float sv = 0.f, sw = 0.f;
    #pragma unroll
    for (int u = 0; u < 8; u++) { sv += gv[t][u]; sw += gw[t][u]; }
    fusedS[i][256 + cg] = sv / sw;
  }

  int g = t >> 8, o = t & 255;            // group g: positions 4g..4g+3
  float a4[4] = {0.f, 0.f, 0.f, 0.f};
  const float4* wo4 = (const float4*)(bw + (size_t)o * 192);
  for (int cr = 0; cr < 24; cr++) {       // conv 8x8 s8
    const float* prow = &patch[cr * 64 + g * 32];
    #pragma unroll
    for (int half = 0; half < 2; half++) {
      float4 w4 = wo4[cr*2 + half];
      #pragma unroll
      for (int e = 0; e < 4; e++) {
        float wv = (&w4.x)[e];
        int cl = half*4 + e;
        #pragma unroll
        for (int i4 = 0; i4 < 4; i4++) a4[i4] += wv * prow[i4*8 + cl];
      }
    }
  }
  float bias = bb[o];
  #pragma unroll
  for (int i4 = 0; i4 < 4; i4++) fusedS[g*4 + i4][o] = fmaxf(a4[i4] + bias, 0.f);
  __syncthreads();

  #pragma unroll
  for (int i4 = 0; i4 < 4; i4++) a4[i4] = 0.f;
  const float4* fwo4 = (const float4*)(fwp + (size_t)o * 264);
  for (int c4 = 0; c4 < 66; c4++) {       // fusion matmul
    float4 w4 = fwo4[c4];
    #pragma unroll
    for (int e = 0; e < 4; e++) {
      float wv = (&w4.x)[e];
      int c = c4*4 + e;
      #pragma unroll
      for (int i4 = 0; i4 < 4; i4++) a4[i4] += wv * fusedS[g*4 + i4][c];
    }
  }
  float fbias = fb[o];
  int lane = t & 63, wid = t >> 6;
  #pragma unroll
  for (int i4 = 0; i4 < 4; i4++) {
    a4[i4] += fbias;
    int p = b*1024 + h*32 + w0 + g*4 + i4;
    flatb[(size_t)p * 256 + o] = f2bf(a4[i4]);
    float s = a4[i4] * a4[i4];
    #pragma unroll
    for (int m = 1; m < 64; m <<= 1) s += __shfl_xor(s, m);
    if (lane == 0) redS[g*4 + i4][wid & 3] = s;
  }
  __syncthreads();
  if (t < 8) {
    float s = redS[t][0] + redS[t][1] + redS[t][2] + redS[t][3];
    int p = b*1024 + h*32 + w0 + t;
    qsq[p] = s;
    float den = fusedS[t][256+3], opa = fusedS[t][256+2], ani = fusedS[t][256+4];
    float base2 = 0.5f*den + 0.25f*(1.f - opa) + 0.25f*ani;
    wgt[p] = 1.f + 1.f/(1.f + expf(-4.f*(base2 - 0.5f)));
  }
}

// ---------------- GEMM-min v3: persistent-A (reg-pinned), fragment-order LDS,
// counted-vmcnt raw-barrier pipeline (T3+T4+T5) -------------------------------
// LDS slot S (16B) of a 32KB subtile: l15=S&15, l4=(S>>4)&3, ks=(S>>6)&7,
// h=(S>>9)&1, wc=S>>10  ->  holds B-row (wc*32+h*16+l15), bytes ks*64+l4*16.
// Reads are then dense 1024B per ds_read_b128 wave-op (conflict-free).
__global__ __launch_bounds__(256, 2) void k_distmin(
    const short* __restrict__ Aq, const short* __restrict__ Bb,
    const float* __restrict__ qsq, const float* __restrict__ msq,
    float* __restrict__ partial)
{
  __shared__ __align__(16) unsigned char sB[2][32768];
  __shared__ float msq_lds[2048];
  __shared__ float red[2][128];
  int t = threadIdx.x;
  int lane = t & 63, wid = t >> 6;
  int wr = wid >> 1, wc = wid & 1;
  const int l15 = lane & 15, l4 = lane >> 4;
  int nc = blockIdx.x, mt = blockIdx.y;
  int m0 = mt * 128;
  const size_t nchunk0 = (size_t)nc * CHUNK;
  const unsigned char* Bbyte = (const unsigned char*)Bb + nchunk0 * 512;
  const unsigned char* Abyte = (const unsigned char*)Aq;

  // per-lane loop-invariant global source offsets for the 8 stage instrs
  int soff[8];
  #pragma unroll
  for (int j = 0; j < 8; j++) {
    int sh = j * 4 + wid;                  // 0..31
    int ks = sh & 7, hh = (sh >> 3) & 1, wcs = sh >> 4;
    int n = wcs * 32 + hh * 16 + l15;
    int k = ks * 64 + l4 * 16;
    soff[j] = n * 512 + k;
  }

  // msq chunk -> LDS (2048 floats)
  {
    const float4* src = (const float4*)(msq + nchunk0);
    float4* dst = (float4*)msq_lds;
    dst[t] = src[t];
    dst[t + 256] = src[t + 256];
  }

  // A tile -> registers, pinned against rematerialization
  bf16x8 af[4][8];
  #pragma unroll
  for (int mi = 0; mi < 4; mi++)
    #pragma unroll
    for (int ks = 0; ks < 8; ks++) {
      af[mi][ks] = *(const bf16x8*)(Abyte +
          (size_t)(m0 + wr*64 + mi*16 + l15) * 512 + ks*64 + l4*16);
      asm volatile("" : "+v"(af[mi][ks]));
    }

  float vmin[4][4];
  #pragma unroll
  for (int mi = 0; mi < 4; mi++)
    #pragma unroll
    for (int r = 0; r < 4; r++) vmin[mi][r] = 3.4e38f;

  __syncthreads();   // drains all prologue loads; msq_lds visible to all waves

#define STAGE(bufsel, sidx) do {                                              \
    const unsigned char* gb_ = Bbyte + (size_t)(sidx) * 32768;                \
    unsigned char* lb_ = &sB[bufsel][0] + wid * 1024;                         \
    _Pragma("unroll")                                                         \
    for (int j_ = 0; j_ < 8; j_++) {                                          \
      __builtin_amdgcn_global_load_lds(                                       \
        (const __attribute__((address_space(1))) unsigned int*)(gb_ + soff[j_]), \
        (__attribute__((address_space(3))) unsigned int*)(lb_ + j_*4096),     \
        16, 0, 0);                                                            \
    }                                                                         \
  } while (0)

#define ACQUIRE(N) do {                                                       \
    asm volatile("s_waitcnt vmcnt(" #N ")" ::: "memory");                     \
    __builtin_amdgcn_s_barrier();                                             \
    __builtin_amdgcn_sched_barrier(0);                                        \
  } while (0)

#define RELEASE() do {                                                        \
    asm volatile("s_waitcnt lgkmcnt(0)" ::: "memory");                        \
    __builtin_amdgcn_s_barrier();                                             \
    __builtin_amdgcn_sched_barrier(0);                                        \
  } while (0)

#define COMPUTE(sarg) do {                                                    \
    const unsigned char* buf_ = &sB[(sarg) & 1][0] + wc * 16384;              \
    float m0_ = msq_lds[(sarg) * 64 + wc * 32 + l15];                         \
    float m1_ = msq_lds[(sarg) * 64 + wc * 32 + 16 + l15];                    \
    f32x4 acc_[4][2];                                                         \
    _Pragma("unroll")                                                         \
    for (int mi = 0; mi < 4; mi++) {                                          \
      acc_[mi][0] = (f32x4){0.f,0.f,0.f,0.f};                                 \
      acc_[mi][1] = (f32x4){0.f,0.f,0.f,0.f};                                 \
    }                                                                         \
    __builtin_amdgcn_s_setprio(1);                                            \
    _Pragma("unroll")                                                         \
    for (int ks = 0; ks < 8; ks++) {                                          \
      bf16x8 b0_ = *(const bf16x8*)(buf_ + ks*1024 + l4*256 + l15*16);        \
      bf16x8 b1_ = *(const bf16x8*)(buf_ + 8192 + ks*1024 + l4*256 + l15*16); \
      _Pragma("unroll")                                                       \
      for (int mi = 0; mi < 4; mi++) {                                        \
        acc_[mi][0] = __builtin_amdgcn_mfma_f32_16x16x32_bf16(af[mi][ks], b0_, acc_[mi][0], 0, 0, 0); \
        acc_[mi][1] = __builtin_amdgcn_mfma_f32_16x16x32_bf16(af[mi][ks], b1_, acc_[mi][1], 0, 0, 0); \
      }                                                                       \
    }                                                                         \
    __builtin_amdgcn_s_setprio(0);                                            \
    _Pragma("unroll")                                                         \
    for (int mi = 0; mi < 4; mi++)                                            \
      _Pragma("unroll")                                                       \
      for (int r = 0; r < 4; r++)                                             \
        vmin[mi][r] = fminf(vmin[mi][r],                                      \
            fminf(m0_ - 2.f*acc_[mi][0][r], m1_ - 2.f*acc_[mi][1][r]));       \
  } while (0)

  STAGE(0, 0);
  STAGE(1, 1);

  for (int s = 0; s < NSUB - 2; s++) {
    ACQUIRE(8);                 // STAGE(s) landed (8 newer may stay in flight)
    COMPUTE(s);
    RELEASE();                  // all waves done reading buf[s&1]
    STAGE(s & 1, s + 2);
  }
  ACQUIRE(8);
  COMPUTE(NSUB - 2);
  ACQUIRE(0);                   // drain final stage
  COMPUTE(NSUB - 1);

#undef STAGE
#undef ACQUIRE
#undef RELEASE
#undef COMPUTE

  // deferred cross-lane min over the 16 l15 columns
  #pragma unroll
  for (int mi = 0; mi < 4; mi++)
    #pragma unroll
    for (int r = 0; r < 4; r++) {
      float v = vmin[mi][r];
      v = fminf(v, __shfl_xor(v, 1));
      v = fminf(v, __shfl_xor(v, 2));
      v = fminf(v, __shfl_xor(v, 4));
      v = fminf(v, __shfl_xor(v, 8));
      if (l15 == 0) red[wc][wr * 64 + mi * 16 + l4 * 4 + r] = v;
    }
  __syncthreads();
  if (t < 128) {
    float v = fminf(red[0][t], red[1][t]);
    float d2 = qsq[m0 + t] + v;
    partial[(size_t)(m0 + t) * NCHUNKS + nc] = fmaxf(d2, 0.f);
  }
}

// ---------------- final min + sqrt + geo weight -----------------------------
__global__ __launch_bounds__(256) void k_final(
    const float* __restrict__ partial, const float* __restrict__ wgt,
    float* __restrict__ out)
{
  int q = blockIdx.x * 256 + threadIdx.x;        // 2048
  const float4* p = (const float4*)(partial + (size_t)q * NCHUNKS);
  float v = 3.4e38f;
  #pragma unroll
  for (int j = 0; j < 8; j++) {
    float4 x = p[j];
    v = fminf(v, fminf(fminf(x.x, x.y), fminf(x.z, x.w)));
  }
  float sp = sqrtf(v);
  out[q] = sp;
  out[NP + q] = sp * wgt[q];
}

extern "C" void kernel_launch(void* const* d_in, const int* in_sizes, int n_in,
                              void* d_out, int out_size, void* d_ws, size_t ws_size,
                              hipStream_t stream) {
  const float* image    = (const float*)d_in[0];
  const float* geometry = (const float*)d_in[1];
  const float* bw       = (const float*)d_in[2];
  const float* bb       = (const float*)d_in[3];
  const float* fw       = (const float*)d_in[4];
  const float* fb       = (const float*)d_in[5];
  const float* mb       = (const float*)d_in[6];
  float* out = (float*)d_out;
  char* ws = (char*)d_ws;

  float* wgt     = (float*)(ws);                  // 8 KB
  float* qsq     = (float*)(ws + 8192);           // 8 KB
  float* msq     = (float*)(ws + 16384);          // 256 KB
  float* fwp     = (float*)(ws + 278528);         // 270336 B
  short* flatb   = (short*)(ws + 548864);         // 1 MB
  float* partial = (float*)(ws + 1597440);        // 256 KB [2048][32]
  short* mbb     = (short*)(ws + 1859584);        // 32 MB  [65536][256] bf16

  hipLaunchKernelGGL(k_repack_fw, dim3(264),     dim3(256), 0, stream, fw, fwp);
  hipLaunchKernelGGL(k_prep,      dim3(8448),    dim3(512), 0, stream,
                     image, geometry, bw, bb, fwp, fb, mb, flatb, qsq, wgt, mbb, msq);
  hipLaunchKernelGGL(k_distmin,   dim3(32, 16),  dim3(256), 0, stream, flatb, mbb, qsq, msq, partial);
  hipLaunchKernelGGL(k_final,     dim3(8),       dim3(256), 0, stream, partial, wgt, out);
}